// Round 2
// baseline (2528.724 us; speedup 1.0000x reference)
//
#include <hip/hip_runtime.h>
#include <math.h>

// GNN_node_Virtualnode: B=128 graphs, 256 nodes/graph, 2048 edges/graph,
// emb=256, 5 GIN layers + virtual node, learned dense-adjacency propagation.
// Workspace need: ~170 MB.
// d_in[3] (order) is fixed at 3 by the harness; launch count is hardcoded
// (a device scalar cannot drive host launch count under graph capture).

#define B_G   128
#define NPG   256
#define EPG   2048
#define EMB   256
#define NL    5
#define NNODE (B_G*NPG)   // 32768
#define NEDGE (B_G*EPG)   // 262144
#define FBUF  8388608     // floats per 33.55MB buffer

// ---------------- helpers ----------------
__device__ __forceinline__ float4 f4fma(float a, float4 b, float4 c) {
  c.x = fmaf(a, b.x, c.x); c.y = fmaf(a, b.y, c.y);
  c.z = fmaf(a, b.z, c.z); c.w = fmaf(a, b.w, c.w);
  return c;
}

__global__ void k_zero(uint4* p, int n16) {
  int i = blockIdx.x * 256 + threadIdx.x;
  if (i < n16) p[i] = make_uint4(0, 0, 0, 0);
}

// 16-entry sigmoid edge-weight table (ea has only 16 values)
__global__ void k_ewtbl(const float* __restrict__ bh, const float* __restrict__ w,
                        const float* __restrict__ b, float* __restrict__ tbl) {
  int t = threadIdx.x; // 64 threads = 1 wave
  for (int v = 0; v < 16; v++) {
    float p = bh[v * 64 + t] * w[t];
    for (int off = 32; off; off >>= 1) p += __shfl_down(p, off, 64);
    if (t == 0) tbl[v] = 1.0f / (1.0f + expf(-(p + b[0])));
  }
}

// Deterministic duplicate resolution: last edge (max e) wins, matching
// sequential .at[s,d].set(w) semantics. Pack (e+1)<<4 | eav, atomicMax.
__global__ void k_pack_adj(const int* __restrict__ lei, const int* __restrict__ ea,
                           int* __restrict__ packed) {
  int idx = blockIdx.x * 256 + threadIdx.x;       // NEDGE
  int g = idx >> 11, e = idx & 2047;
  int s = lei[g * 4096 + e];
  int d = lei[g * 4096 + 2048 + e];
  int v = ((e + 1) << 4) | ea[g * 2048 + e];
  atomicMax(&packed[g * 65536 + s * 256 + d], v);
}

__global__ void k_unpack_adj(const int* __restrict__ packed,
                             const float* __restrict__ tbl, float* __restrict__ adj) {
  int idx = blockIdx.x * 256 + threadIdx.x;       // 8388608
  int v = packed[idx];
  if (v) adj[idx] = tbl[v & 15];
}

__global__ void k_addeye(float* __restrict__ adj) {
  int idx = blockIdx.x * 256 + threadIdx.x;       // NNODE
  int g = idx >> 8, i = idx & 255;
  adj[g * 65536 + i * 257] += 1.0f;
}

// A[i][j] = colsum(i)^-1/2 * adj[i][j] * rowsum(j)^-1/2  (in place)
__global__ __launch_bounds__(256)
void k_degnorm(float* __restrict__ adj) {
  int g = blockIdx.x, t = threadIdx.x;
  float* Ag = adj + (size_t)g * 65536;
  __shared__ float cs[256];
  float s0 = 0, s1 = 0, s2 = 0, s3 = 0;          // 4-deep ILP (128 blocks only;
  for (int i = 0; i < 256; i += 4) {             //  latency not hidden by TLP)
    s0 += Ag[(i + 0) * 256 + t]; s1 += Ag[(i + 1) * 256 + t];
    s2 += Ag[(i + 2) * 256 + t]; s3 += Ag[(i + 3) * 256 + t];
  }
  cs[t] = rsqrtf((s0 + s1) + (s2 + s3));          // colsum(t)^-1/2
  float4 r0 = make_float4(0, 0, 0, 0), r1 = r0, r2 = r0, r3 = r0;
  const float4* A4 = (const float4*)(Ag + t * 256);
  for (int j = 0; j < 64; j += 4) {
    float4 v0 = A4[j], v1 = A4[j + 1], v2 = A4[j + 2], v3 = A4[j + 3];
    r0.x += v0.x + v0.y; r0.y += v0.z + v0.w;
    r1.x += v1.x + v1.y; r1.y += v1.z + v1.w;
    r2.x += v2.x + v2.y; r2.y += v2.z + v2.w;
    r3.x += v3.x + v3.y; r3.y += v3.z + v3.w;
  }
  float rc = rsqrtf((r0.x + r0.y) + (r1.x + r1.y) + (r2.x + r2.y) + (r3.x + r3.y));
  __syncthreads();
  for (int i = 0; i < 256; i++) Ag[i * 256 + t] = cs[i] * Ag[i * 256 + t] * rc;
}

// fea gather: X0 = Y = atom_emb[atom_idx]
__global__ void k_fea(const int* __restrict__ aidx, const float* __restrict__ aemb,
                      float* __restrict__ X0, float* __restrict__ Y) {
  int i = blockIdx.x * 256 + threadIdx.x;          // 2097152 float4s
  int node = i >> 6, d4 = (i & 63) * 4;
  int av = aidx[node];
  float4 v = *(const float4*)&aemb[av * 256 + d4];
  *(float4*)&X0[(size_t)i * 4] = v;
  *(float4*)&Y[(size_t)i * 4] = v;
}

// Generic fp32 GEMM: C[z] = op_A(A[z]) @ B[z] + bias ; optional Yacc += C.
// op_A (ascale!=null): a = relu(a*ascale[k]+ashift[k])  (BN+relu fold on A load)
// block: 256 thr; tile 32 rows x 256 cols; thread: 8 rows x 4 cols (float4)
__global__ __launch_bounds__(256)
void k_gemm(const float* __restrict__ A, const float* __restrict__ B,
            const float* __restrict__ bias, float* __restrict__ C,
            float* __restrict__ Yacc,
            int M, int N, int K, int sA, int sB, int sC,
            const float* __restrict__ ascale, const float* __restrict__ ashift) {
  int z = blockIdx.z;
  A += (size_t)z * sA; B += (size_t)z * sB; C += (size_t)z * sC;
  float* Yp = Yacc ? Yacc + (size_t)z * sC : nullptr;
  int rowbase = blockIdx.y * 32;
  int colbase = blockIdx.x * 256;
  int t = threadIdx.x;
  int cl = t & 63, rg = t >> 6;
  int col = colbase + cl * 4;
  __shared__ float As[32][64];
  float4 acc[8];
#pragma unroll
  for (int r = 0; r < 8; r++) acc[r] = make_float4(0, 0, 0, 0);
  for (int k0 = 0; k0 < K; k0 += 64) {
#pragma unroll
    for (int i = 0; i < 8; i++) {
      int id = i * 256 + t;
      int r = id >> 6, kk = id & 63;
      float v = A[(rowbase + r) * K + k0 + kk];
      if (ascale) {
        v = fmaf(v, ascale[k0 + kk], ashift[k0 + kk]);
        v = v > 0.0f ? v : 0.0f;
      }
      As[r][kk] = v;
    }
    __syncthreads();
#pragma unroll 4
    for (int kk = 0; kk < 64; kk += 4) {
      const float* Bp = B + (k0 + kk) * N + col;
      float4 b0 = *(const float4*)(Bp);
      float4 b1 = *(const float4*)(Bp + N);
      float4 b2 = *(const float4*)(Bp + 2 * N);
      float4 b3 = *(const float4*)(Bp + 3 * N);
#pragma unroll
      for (int r = 0; r < 8; r++) {
        float4 a4 = *(const float4*)&As[rg * 8 + r][kk];
        acc[r] = f4fma(a4.x, b0, acc[r]);
        acc[r] = f4fma(a4.y, b1, acc[r]);
        acc[r] = f4fma(a4.z, b2, acc[r]);
        acc[r] = f4fma(a4.w, b3, acc[r]);
      }
    }
    __syncthreads();
  }
  float4 bi = make_float4(0, 0, 0, 0);
  if (bias) bi = *(const float4*)&bias[col];
#pragma unroll
  for (int r = 0; r < 8; r++) {
    int row = rowbase + rg * 8 + r;
    size_t idx = (size_t)row * N + col;
    float4 o = acc[r];
    o.x += bi.x; o.y += bi.y; o.z += bi.z; o.w += bi.w;
    if (Yp) {
      float4 yv = *(float4*)&Yp[idx];
      yv.x += o.x; yv.y += o.y; yv.z += o.z; yv.w += o.w;
      *(float4*)&Yp[idx] = yv;
    }
    *(float4*)&C[idx] = o;
  }
}

// ---- CSR build (edge structure is layer-invariant; built once) ----
__global__ void k_count(const int* __restrict__ lei, int* __restrict__ counts) {
  int idx = blockIdx.x * 256 + threadIdx.x;
  int g = idx >> 11, e = idx & 2047;
  int d = lei[g * 4096 + 2048 + e];
  atomicAdd(&counts[g * 256 + d], 1);
}

__global__ void k_scan(const int* __restrict__ counts, int* __restrict__ rowptr,
                       int* __restrict__ pos) {
  int g = blockIdx.x, t = threadIdx.x;
  __shared__ int sc[256];
  int own = counts[g * 256 + t];
  sc[t] = own;
  __syncthreads();
  for (int off = 1; off < 256; off <<= 1) {
    int v = 0;
    if (t >= off) v = sc[t - off];
    __syncthreads();
    sc[t] += v;
    __syncthreads();
  }
  int val = g * 2048 + sc[t] - own; // exclusive
  rowptr[g * 256 + t] = val;
  pos[g * 256 + t] = val;
  if (g == B_G - 1 && t == 255) rowptr[B_G * 256] = B_G * 2048;
}

__global__ void k_fill(const int* __restrict__ lei, const int* __restrict__ ea,
                       int* __restrict__ pos, int* __restrict__ csr) {
  int idx = blockIdx.x * 256 + threadIdx.x;
  int g = idx >> 11, e = idx & 2047;
  int s = lei[g * 4096 + e];
  int d = lei[g * 4096 + 2048 + e];
  int eav = ea[g * 2048 + e];
  int slot = atomicAdd(&pos[g * 256 + d], 1);
  csr[slot] = s | (eav << 16);
}

// z = (1+eps)*(h+vn) + sum_{e->this} relu(h[src]+vn+eemb[ea])
// h = transform(src buffer): hsc? relu(x*hsc[c]+hsh[c]) : x*hmul
__global__ __launch_bounds__(256)
void k_agg(const float* __restrict__ H, float hmul,
           const float* __restrict__ hsc, const float* __restrict__ hsh,
           const float* __restrict__ vn, int vns,
           const float* __restrict__ eemb,
           const int* __restrict__ rowptr, const int* __restrict__ csr,
           const float* __restrict__ geps, int l, float* __restrict__ Z) {
  __shared__ float ee[16 * 256];
  for (int i = threadIdx.x; i < 4096; i += 256) ee[i] = eemb[i];
  __syncthreads();
  int lane = threadIdx.x & 63, w = threadIdx.x >> 6;
  int m = blockIdx.x * 4 + w;
  int g = m >> 8;
  int d = lane * 4;
  float eps1 = 1.0f + geps[l];
  float4 sc4 = make_float4(0, 0, 0, 0), sh4 = make_float4(0, 0, 0, 0);
  if (hsc) { sc4 = *(const float4*)&hsc[d]; sh4 = *(const float4*)&hsh[d]; }
  float4 vn4 = *(const float4*)&vn[(size_t)g * vns + d];
  int rp = rowptr[m], rp1 = rowptr[m + 1];
  float4 acc = make_float4(0, 0, 0, 0);
  int gbase = g << 8;
  for (int j = rp; j < rp1; j++) {
    int cw = csr[j];
    int src = cw & 0xFFFF, eav = cw >> 16;
    float4 h4 = *(const float4*)&H[(size_t)(gbase + src) * 256 + d];
    if (hsc) {
      h4.x = fmaf(h4.x, sc4.x, sh4.x); h4.y = fmaf(h4.y, sc4.y, sh4.y);
      h4.z = fmaf(h4.z, sc4.z, sh4.z); h4.w = fmaf(h4.w, sc4.w, sh4.w);
      h4.x = h4.x > 0 ? h4.x : 0; h4.y = h4.y > 0 ? h4.y : 0;
      h4.z = h4.z > 0 ? h4.z : 0; h4.w = h4.w > 0 ? h4.w : 0;
    } else {
      h4.x *= hmul; h4.y *= hmul; h4.z *= hmul; h4.w *= hmul;
    }
    const float4 e4 = *(const float4*)&ee[eav * 256 + d];
    float mx = h4.x + vn4.x + e4.x; float my = h4.y + vn4.y + e4.y;
    float mz = h4.z + vn4.z + e4.z; float mw = h4.w + vn4.w + e4.w;
    acc.x += mx > 0 ? mx : 0; acc.y += my > 0 ? my : 0;
    acc.z += mz > 0 ? mz : 0; acc.w += mw > 0 ? mw : 0;
  }
  float4 hs = *(const float4*)&H[(size_t)m * 256 + d];
  if (hsc) {
    hs.x = fmaf(hs.x, sc4.x, sh4.x); hs.y = fmaf(hs.y, sc4.y, sh4.y);
    hs.z = fmaf(hs.z, sc4.z, sh4.z); hs.w = fmaf(hs.w, sc4.w, sh4.w);
    hs.x = hs.x > 0 ? hs.x : 0; hs.y = hs.y > 0 ? hs.y : 0;
    hs.z = hs.z > 0 ? hs.z : 0; hs.w = hs.w > 0 ? hs.w : 0;
  } else {
    hs.x *= hmul; hs.y *= hmul; hs.z *= hmul; hs.w *= hmul;
  }
  float4 z4;
  z4.x = eps1 * (hs.x + vn4.x) + acc.x;
  z4.y = eps1 * (hs.y + vn4.y) + acc.y;
  z4.z = eps1 * (hs.z + vn4.z) + acc.z;
  z4.w = eps1 * (hs.w + vn4.w) + acc.w;
  *(float4*)&Z[(size_t)m * 256 + d] = z4;
}

// vn_out = relu(relu(vt@W1+B1)@W2+B2), vt = colsum_nodes(h) + 257*vn
__global__ __launch_bounds__(256)
void k_vn(const float* __restrict__ H, float hmul,
          const float* __restrict__ hsc, const float* __restrict__ hsh,
          const float* __restrict__ vn_in, int vns,
          const float* __restrict__ W1, const float* __restrict__ B1,
          const float* __restrict__ W2, const float* __restrict__ B2,
          float* __restrict__ vn_out) {
  int g = blockIdx.x, t = threadIdx.x;
  __shared__ float vt[256];
  __shared__ float u[512];
  float sc = 0, sh = 0;
  if (hsc) { sc = hsc[t]; sh = hsh[t]; }
  float s0 = 0, s1 = 0, s2 = 0, s3 = 0;           // 4-deep ILP
  for (int i = 0; i < 256; i += 4) {
    float v0 = H[(size_t)(g * 256 + i + 0) * 256 + t];
    float v1 = H[(size_t)(g * 256 + i + 1) * 256 + t];
    float v2 = H[(size_t)(g * 256 + i + 2) * 256 + t];
    float v3 = H[(size_t)(g * 256 + i + 3) * 256 + t];
    if (hsc) {
      v0 = fmaf(v0, sc, sh); v0 = v0 > 0 ? v0 : 0;
      v1 = fmaf(v1, sc, sh); v1 = v1 > 0 ? v1 : 0;
      v2 = fmaf(v2, sc, sh); v2 = v2 > 0 ? v2 : 0;
      v3 = fmaf(v3, sc, sh); v3 = v3 > 0 ? v3 : 0;
    } else { v0 *= hmul; v1 *= hmul; v2 *= hmul; v3 *= hmul; }
    s0 += v0; s1 += v1; s2 += v2; s3 += v3;
  }
  vt[t] = (s0 + s1) + (s2 + s3) + 257.0f * vn_in[(size_t)g * vns + t];
  __syncthreads();
  for (int o = t; o < 512; o += 256) {
    float a = B1[o];
    for (int k = 0; k < 256; k++) a = fmaf(vt[k], W1[k * 512 + o], a);
    u[o] = a > 0 ? a : 0;
  }
  __syncthreads();
  float a = B2[t];
  for (int k = 0; k < 512; k++) a = fmaf(u[k], W2[k * 256 + t], a);
  vn_out[g * 256 + t] = a > 0 ? a : 0;
}

// column sums + sumsq (atomic partials; dest pre-zeroed)
__global__ __launch_bounds__(256)
void k_colstats(const float* __restrict__ X, int NC,
                float* __restrict__ Ssum, float* __restrict__ Ssq) {
  int cl = threadIdx.x & 63, rl = threadIdx.x >> 6;
  int col = blockIdx.x * 64 + cl;
  int rbase = blockIdx.y * 1024;
  float s = 0, q = 0;
  for (int i = 0; i < 256; i++) {
    float v = X[(size_t)(rbase + rl + i * 4) * NC + col];
    s += v; q += v * v;
  }
  __shared__ float rs[4][64], rq[4][64];
  rs[rl][cl] = s; rq[rl][cl] = q;
  __syncthreads();
  if (rl == 0) {
    s = rs[0][cl] + rs[1][cl] + rs[2][cl] + rs[3][cl];
    q = rq[0][cl] + rq[1][cl] + rq[2][cl] + rq[3][cl];
    atomicAdd(&Ssum[col], s);
    atomicAdd(&Ssq[col], q);
  }
}

__global__ void k_bnfin(const float* __restrict__ Ssum, const float* __restrict__ Ssq,
                        const float* __restrict__ g, const float* __restrict__ b,
                        float* __restrict__ scale, float* __restrict__ shift,
                        int NC, float invN) {
  int c = blockIdx.x * 256 + threadIdx.x;
  if (c >= NC) return;
  float mu = Ssum[c] * invN;
  float var = Ssq[c] * invN - mu * mu;
  float rs = rsqrtf(var + 1e-5f);
  float s = rs * g[c];
  scale[c] = s;
  shift[c] = b[c] - mu * s;
}

// out = t2*sc[c]+sh[c] (final BN, JK='last', no relu)
__global__ void k_final(const float* __restrict__ T2, const float* __restrict__ sc,
                        const float* __restrict__ sh, float* __restrict__ out) {
  int i = blockIdx.x * 256 + threadIdx.x; // 2097152 float4s
  int c4 = (i & 63) * 4;
  float4 v = *(const float4*)&T2[(size_t)i * 4];
  float4 s4 = *(const float4*)&sc[c4];
  float4 h4 = *(const float4*)&sh[c4];
  v.x = fmaf(v.x, s4.x, h4.x); v.y = fmaf(v.y, s4.y, h4.y);
  v.z = fmaf(v.z, s4.z, h4.z); v.w = fmaf(v.w, s4.w, h4.w);
  *(float4*)&out[(size_t)i * 4] = v;
}

extern "C" void kernel_launch(void* const* d_in, const int* in_sizes, int n_in,
                              void* d_out, int out_size, void* d_ws, size_t ws_size,
                              hipStream_t stream) {
  (void)in_sizes; (void)n_in; (void)out_size; (void)ws_size;
  const int*   atom_idx = (const int*)d_in[0];
  const int*   lei      = (const int*)d_in[1];
  const int*   eattr    = (const int*)d_in[2];
  const float* atom_emb = (const float*)d_in[4];
  const float* bemb_h   = (const float*)d_in[5];
  const float* elw      = (const float*)d_in[6];
  const float* elb      = (const float*)d_in[7];
  const float* bemb_l   = (const float*)d_in[8];
  const float* geps     = (const float*)d_in[9];
  const float* mw1      = (const float*)d_in[10];
  const float* mb1      = (const float*)d_in[11];
  const float* mbng     = (const float*)d_in[12];
  const float* mbnb     = (const float*)d_in[13];
  const float* mw2      = (const float*)d_in[14];
  const float* mb2      = (const float*)d_in[15];
  const float* obng     = (const float*)d_in[16];
  const float* obnb     = (const float*)d_in[17];
  const float* vne      = (const float*)d_in[18];
  const float* vw1      = (const float*)d_in[19];
  const float* vb1      = (const float*)d_in[20];
  const float* vw2      = (const float*)d_in[21];
  const float* vb2      = (const float*)d_in[22];
  float* out = (float*)d_out;

  // ws layout (floats). A_ is reused as T2; X0..X1 reused as T1 (67MB);
  // Z_ doubles as the packed-adjacency int scratch before layer 0.
  float* W   = (float*)d_ws;
  float* A_  = W;
  float* X0  = W + (size_t)FBUF;
  float* X1  = W + (size_t)2 * FBUF;
  float* Y_  = W + (size_t)3 * FBUF;
  float* Z_  = W + (size_t)4 * FBUF;
  float* SM  = W + (size_t)5 * FBUF;
  float* EWT = SM;             // 16
  float* S1S = SM + 16;        // 512
  float* S1Q = S1S + 512;      // 512
  float* S2S = S1Q + 512;      // 256
  float* S2Q = S2S + 256;      // 256
  float* SC1 = S2Q + 256;      // 512
  float* SH1 = SC1 + 512;      // 512
  float* SC2 = SH1 + 512;      // 256
  float* SH2 = SC2 + 256;      // 256
  float* VNA = SH2 + 256;      // 32768
  float* VNB = VNA + 32768;    // 32768
  int* ROWPTR = (int*)(VNB + 32768); // 32769 (+pad)
  int* POS    = ROWPTR + 32772;
  int* COUNTS = POS + 32768;
  int* CSR    = COUNTS + 32768;      // 262144
  float* T1 = X0;   // 16.78M floats spanning X0+X1
  float* T2 = A_;
  int* PACKED = (int*)Z_;            // 8.39M ints, dead before layer-0 k_agg

  // ---- stage 1: dense learned-adjacency propagation ----
  k_zero<<<8192, 256, 0, stream>>>((uint4*)A_, 2097152);
  k_zero<<<8192, 256, 0, stream>>>((uint4*)PACKED, 2097152);
  k_zero<<<32, 256, 0, stream>>>((uint4*)COUNTS, 8192);
  k_ewtbl<<<1, 64, 0, stream>>>(bemb_h, elw, elb, EWT);
  k_pack_adj<<<NEDGE / 256, 256, 0, stream>>>(lei, eattr, PACKED);
  k_unpack_adj<<<32768, 256, 0, stream>>>(PACKED, EWT, A_);
  k_addeye<<<NNODE / 256, 256, 0, stream>>>(A_);
  k_degnorm<<<B_G, 256, 0, stream>>>(A_);
  k_fea<<<8192, 256, 0, stream>>>(atom_idx, atom_emb, X0, Y_);
  // order = 3 (fixed): x = A@x thrice, Y accumulates
  k_gemm<<<dim3(1, 8, B_G), 256, 0, stream>>>(A_, X0, nullptr, X1, Y_,
      256, 256, 256, 65536, 65536, 65536, nullptr, nullptr);
  k_gemm<<<dim3(1, 8, B_G), 256, 0, stream>>>(A_, X1, nullptr, X0, Y_,
      256, 256, 256, 65536, 65536, 65536, nullptr, nullptr);
  k_gemm<<<dim3(1, 8, B_G), 256, 0, stream>>>(A_, X0, nullptr, X1, Y_,
      256, 256, 256, 65536, 65536, 65536, nullptr, nullptr);

  // ---- CSR (once; edges invariant across layers) ----
  k_count<<<NEDGE / 256, 256, 0, stream>>>(lei, COUNTS);
  k_scan<<<B_G, 256, 0, stream>>>(COUNTS, ROWPTR, POS);
  k_fill<<<NEDGE / 256, 256, 0, stream>>>(lei, eattr, POS, CSR);

  // ---- GIN + virtual-node stack ----
  const float* vn_cur = vne; int vns = 0;   // layer0 vn = vn_emb broadcast
  float* vn_next = VNA;
  for (int l = 0; l < NL; l++) {
    const float* hsrc = (l == 0) ? Y_ : T2;
    const float* hsc  = (l == 0) ? nullptr : SC2;
    const float* hsh  = (l == 0) ? nullptr : SH2;
    k_agg<<<NNODE / 4, 256, 0, stream>>>(hsrc, 0.25f, hsc, hsh, vn_cur, vns,
        bemb_l + (size_t)l * 16 * EMB, ROWPTR, CSR, geps, l, Z_);
    if (l < NL - 1)
      k_vn<<<B_G, 256, 0, stream>>>(hsrc, 0.25f, hsc, hsh, vn_cur, vns,
          vw1 + (size_t)l * EMB * 512, vb1 + (size_t)l * 512,
          vw2 + (size_t)l * 512 * EMB, vb2 + (size_t)l * EMB, vn_next);
    k_zero<<<2, 256, 0, stream>>>((uint4*)S1S, 384); // both stat sets
    k_gemm<<<dim3(2, NNODE / 32, 1), 256, 0, stream>>>(Z_, mw1 + (size_t)l * EMB * 512,
        mb1 + (size_t)l * 512, T1, nullptr, NNODE, 512, EMB, 0, 0, 0, nullptr, nullptr);
    k_colstats<<<dim3(8, 32), 256, 0, stream>>>(T1, 512, S1S, S1Q);
    k_bnfin<<<2, 256, 0, stream>>>(S1S, S1Q, mbng + (size_t)l * 512,
        mbnb + (size_t)l * 512, SC1, SH1, 512, 1.0f / NNODE);
    k_gemm<<<dim3(1, NNODE / 32, 1), 256, 0, stream>>>(T1, mw2 + (size_t)l * 512 * EMB,
        mb2 + (size_t)l * EMB, T2, nullptr, NNODE, EMB, 512, 0, 0, 0, SC1, SH1);
    k_colstats<<<dim3(4, 32), 256, 0, stream>>>(T2, 256, S2S, S2Q);
    k_bnfin<<<1, 256, 0, stream>>>(S2S, S2Q, obng + (size_t)l * EMB,
        obnb + (size_t)l * EMB, SC2, SH2, 256, 1.0f / NNODE);
    if (l < NL - 1) {
      vn_cur = vn_next; vns = EMB;
      vn_next = (vn_next == VNA) ? VNB : VNA;
    }
  }
  k_final<<<8192, 256, 0, stream>>>(T2, SC2, SH2, out);
}

// Round 3
// 1769.765 us; speedup vs baseline: 1.4288x; 1.4288x over previous
//
#include <hip/hip_runtime.h>
#include <math.h>

// GNN_node_Virtualnode: B=128 graphs, 256 nodes/graph, 2048 edges/graph,
// emb=256, 5 GIN layers + virtual node, learned dense-adjacency propagation.
// Round 2: all GEMMs -> split-bf16 (3-term) MFMA. Prop runs in transposed
// feature space so the adjacency is its own B-operand layout (no per-step
// transposes); weights pre-transposed once per launch.

#define B_G   128
#define NPG   256
#define EPG   2048
#define EMB   256
#define NL    5
#define NNODE (B_G*NPG)   // 32768
#define NEDGE (B_G*EPG)   // 262144
#define FBUF  8388608     // floats per 33.55MB buffer

typedef __attribute__((ext_vector_type(8))) short bf16x8;
typedef __attribute__((ext_vector_type(4))) float f32x4;

// ---------------- helpers ----------------
__device__ __forceinline__ void split1(float x, unsigned short& h, unsigned short& l) {
  // round-to-nearest-even bf16 hi, then bf16(residual)
  unsigned u = __builtin_bit_cast(unsigned, x);
  unsigned hr = u + 0x7FFFu + ((u >> 16) & 1u);
  h = (unsigned short)(hr >> 16);
  float hf = __builtin_bit_cast(float, hr & 0xFFFF0000u);
  float r = x - hf;
  unsigned v = __builtin_bit_cast(unsigned, r);
  unsigned lr = v + 0x7FFFu + ((v >> 16) & 1u);
  l = (unsigned short)(lr >> 16);
}

__global__ void k_zero(uint4* p, int n16) {
  int i = blockIdx.x * 256 + threadIdx.x;
  if (i < n16) p[i] = make_uint4(0, 0, 0, 0);
}

// 16-entry sigmoid edge-weight table (ea has only 16 values)
__global__ void k_ewtbl(const float* __restrict__ bh, const float* __restrict__ w,
                        const float* __restrict__ b, float* __restrict__ tbl) {
  int t = threadIdx.x; // 64 threads = 1 wave
  for (int v = 0; v < 16; v++) {
    float p = bh[v * 64 + t] * w[t];
    for (int off = 32; off; off >>= 1) p += __shfl_down(p, off, 64);
    if (t == 0) tbl[v] = 1.0f / (1.0f + expf(-(p + b[0])));
  }
}

// Deterministic duplicate resolution: last edge (max e) wins, matching
// sequential .at[s,d].set(w) semantics. Pack (e+1)<<4 | eav, atomicMax.
__global__ void k_pack_adj(const int* __restrict__ lei, const int* __restrict__ ea,
                           int* __restrict__ packed) {
  int idx = blockIdx.x * 256 + threadIdx.x;       // NEDGE
  int g = idx >> 11, e = idx & 2047;
  int s = lei[g * 4096 + e];
  int d = lei[g * 4096 + 2048 + e];
  int v = ((e + 1) << 4) | ea[g * 2048 + e];
  atomicMax(&packed[g * 65536 + s * 256 + d], v);
}

__global__ void k_unpack_adj(const int* __restrict__ packed,
                             const float* __restrict__ tbl, float* __restrict__ adj) {
  int idx = blockIdx.x * 256 + threadIdx.x;       // 8388608
  int v = packed[idx];
  if (v) adj[idx] = tbl[v & 15];
}

__global__ void k_addeye(float* __restrict__ adj) {
  int idx = blockIdx.x * 256 + threadIdx.x;       // NNODE
  int g = idx >> 8, i = idx & 255;
  adj[g * 65536 + i * 257] += 1.0f;
}

// A[i][j] = colsum(i)^-1/2 * adj[i][j] * rowsum(j)^-1/2  (in place)
__global__ __launch_bounds__(256)
void k_degnorm(float* __restrict__ adj) {
  int g = blockIdx.x, t = threadIdx.x;
  float* Ag = adj + (size_t)g * 65536;
  __shared__ float cs[256];
  float s0 = 0, s1 = 0, s2 = 0, s3 = 0;
  for (int i = 0; i < 256; i += 4) {
    s0 += Ag[(i + 0) * 256 + t]; s1 += Ag[(i + 1) * 256 + t];
    s2 += Ag[(i + 2) * 256 + t]; s3 += Ag[(i + 3) * 256 + t];
  }
  cs[t] = rsqrtf((s0 + s1) + (s2 + s3));          // colsum(t)^-1/2
  float4 r0 = make_float4(0, 0, 0, 0), r1 = r0, r2 = r0, r3 = r0;
  const float4* A4 = (const float4*)(Ag + t * 256);
  for (int j = 0; j < 64; j += 4) {
    float4 v0 = A4[j], v1 = A4[j + 1], v2 = A4[j + 2], v3 = A4[j + 3];
    r0.x += v0.x + v0.y; r0.y += v0.z + v0.w;
    r1.x += v1.x + v1.y; r1.y += v1.z + v1.w;
    r2.x += v2.x + v2.y; r2.y += v2.z + v2.w;
    r3.x += v3.x + v3.y; r3.y += v3.z + v3.w;
  }
  float rc = rsqrtf((r0.x + r0.y) + (r1.x + r1.y) + (r2.x + r2.y) + (r3.x + r3.y));
  __syncthreads();
  for (int i = 0; i < 256; i++) Ag[i * 256 + t] = cs[i] * Ag[i * 256 + t] * rc;
}

// transposed fea gather: X0t[g][e][n] = Yt[g][e][n] = atom_emb[aidx[g*256+n]][e]
__global__ void k_feaT(const int* __restrict__ aidx, const float* __restrict__ aemb,
                       float* __restrict__ X0t, float* __restrict__ Yt) {
  int i = blockIdx.x * 256 + threadIdx.x;          // 8388608
  int g = i >> 16, e = (i >> 8) & 255, n = i & 255;
  int av = aidx[g * 256 + n];
  float v = aemb[av * 256 + e];
  X0t[i] = v; Yt[i] = v;
}

// generic LDS-tiled transpose: dst[z][N][K] = scale * src[z][K][N]
__global__ __launch_bounds__(256)
void k_transp(const float* __restrict__ src, float* __restrict__ dst,
              int K, int N, long ss, long sd, float scale) {
  __shared__ float tl[64][65];
  src += (size_t)blockIdx.z * ss; dst += (size_t)blockIdx.z * sd;
  int n0 = blockIdx.x * 64, k0 = blockIdx.y * 64;
  int t = threadIdx.x;
  int c = (t & 15) * 4, r = t >> 4;
#pragma unroll
  for (int p = 0; p < 4; p++) {
    int rr = r + p * 16;
    float4 v = *(const float4*)&src[(size_t)(k0 + rr) * N + n0 + c];
    tl[rr][c] = v.x; tl[rr][c + 1] = v.y; tl[rr][c + 2] = v.z; tl[rr][c + 3] = v.w;
  }
  __syncthreads();
#pragma unroll
  for (int p = 0; p < 4; p++) {
    int rr = r + p * 16;
    float4 o;
    o.x = tl[c][rr] * scale;     o.y = tl[c + 1][rr] * scale;
    o.z = tl[c + 2][rr] * scale; o.w = tl[c + 3][rr] * scale;
    *(float4*)&dst[(size_t)(n0 + rr) * K + k0 + c] = o;
  }
}

// ---- split-bf16 MFMA GEMM ----
// C[z][M][N] = op(A[z][M][K]) @ Bt[z][N][K]^T + bias;  optional Yacc += C.
// op (ascale!=null): a = relu(a*ascale[k]+ashift[k])   (BN+relu fold)
// tile 128x128, BK=64, 256 thr = 4 waves (2x2), wave tile 64x64.
// split: A≈Ah+Al, B≈Bh+Bl (bf16); C ≈ AhBh + AhBl + AlBh (3 MFMA/frag).
__global__ __launch_bounds__(256, 2)
void k_mgemm(const float* __restrict__ A, const float* __restrict__ Bt,
             const float* __restrict__ bias, float* __restrict__ C,
             float* __restrict__ Yacc, int K, int N,
             long sA, long sBt, long sC,
             const float* __restrict__ ascale, const float* __restrict__ ashift) {
  __shared__ alignas(16) unsigned short Ah[128 * 64], Al[128 * 64];
  __shared__ alignas(16) unsigned short Bh[128 * 64], Bl[128 * 64];
  int z = blockIdx.z;
  A += (size_t)z * sA; Bt += (size_t)z * sBt; C += (size_t)z * sC;
  float* Yp = Yacc ? Yacc + (size_t)z * sC : nullptr;
  int rowbase = blockIdx.y * 128, colbase = blockIdx.x * 128;
  int t = threadIdx.x, l = t & 63, w = t >> 6;
  int wr = w >> 1, wc = w & 1;
  f32x4 acc[4][4];
#pragma unroll
  for (int i = 0; i < 4; i++)
#pragma unroll
    for (int j = 0; j < 4; j++) acc[i][j] = (f32x4){0, 0, 0, 0};

  for (int k0 = 0; k0 < K; k0 += 64) {
    __syncthreads();
    for (int p = 0; p < 8; p++) {
      int flat = p * 256 + t;                    // 0..2047
      int r = flat >> 4, kq = (flat & 15) * 4;   // row 0..127, k-quad
      float4 va = *(const float4*)&A[(size_t)(rowbase + r) * K + k0 + kq];
      if (ascale) {
        float4 s4 = *(const float4*)&ascale[k0 + kq];
        float4 h4 = *(const float4*)&ashift[k0 + kq];
        va.x = fmaf(va.x, s4.x, h4.x); va.x = va.x > 0 ? va.x : 0;
        va.y = fmaf(va.y, s4.y, h4.y); va.y = va.y > 0 ? va.y : 0;
        va.z = fmaf(va.z, s4.z, h4.z); va.z = va.z > 0 ? va.z : 0;
        va.w = fmaf(va.w, s4.w, h4.w); va.w = va.w > 0 ? va.w : 0;
      }
      int off = ((r * 128 + kq * 2) ^ ((r & 7) << 4)) >> 1;  // short index
      ushort4 hh, ll;
      split1(va.x, hh.x, ll.x); split1(va.y, hh.y, ll.y);
      split1(va.z, hh.z, ll.z); split1(va.w, hh.w, ll.w);
      *(ushort4*)&Ah[off] = hh; *(ushort4*)&Al[off] = ll;
      float4 vb = *(const float4*)&Bt[(size_t)(colbase + r) * K + k0 + kq];
      split1(vb.x, hh.x, ll.x); split1(vb.y, hh.y, ll.y);
      split1(vb.z, hh.z, ll.z); split1(vb.w, hh.w, ll.w);
      *(ushort4*)&Bh[off] = hh; *(ushort4*)&Bl[off] = ll;
    }
    __syncthreads();
#pragma unroll
    for (int ks = 0; ks < 2; ks++) {
      bf16x8 ah[4], al_[4], bh[4], bl[4];
#pragma unroll
      for (int fm = 0; fm < 4; fm++) {
        int r = wr * 64 + fm * 16 + (l & 15);
        int off = (r * 64 + ks * 32 + (l >> 4) * 8) ^ ((r & 7) << 3);
        ah[fm] = *(const bf16x8*)&Ah[off];
        al_[fm] = *(const bf16x8*)&Al[off];
      }
#pragma unroll
      for (int fn = 0; fn < 4; fn++) {
        int c = wc * 64 + fn * 16 + (l & 15);
        int off = (c * 64 + ks * 32 + (l >> 4) * 8) ^ ((c & 7) << 3);
        bh[fn] = *(const bf16x8*)&Bh[off];
        bl[fn] = *(const bf16x8*)&Bl[off];
      }
#pragma unroll
      for (int fm = 0; fm < 4; fm++)
#pragma unroll
        for (int fn = 0; fn < 4; fn++) {
          acc[fm][fn] = __builtin_amdgcn_mfma_f32_16x16x32_bf16(ah[fm], bh[fn], acc[fm][fn], 0, 0, 0);
          acc[fm][fn] = __builtin_amdgcn_mfma_f32_16x16x32_bf16(ah[fm], bl[fn], acc[fm][fn], 0, 0, 0);
          acc[fm][fn] = __builtin_amdgcn_mfma_f32_16x16x32_bf16(al_[fm], bh[fn], acc[fm][fn], 0, 0, 0);
        }
    }
  }
  // epilogue: D row=(l>>4)*4+r4 (+frag offsets), col=l&15
#pragma unroll
  for (int fm = 0; fm < 4; fm++)
#pragma unroll
    for (int r4 = 0; r4 < 4; r4++) {
      int row = rowbase + wr * 64 + fm * 16 + (l >> 4) * 4 + r4;
#pragma unroll
      for (int fn = 0; fn < 4; fn++) {
        int col = colbase + wc * 64 + fn * 16 + (l & 15);
        float v = acc[fm][fn][r4];
        if (bias) v += bias[col];
        size_t idx = (size_t)row * N + col;
        if (Yp) Yp[idx] += v;
        C[idx] = v;
      }
    }
}

// ---- CSR build (edge structure is layer-invariant; built once) ----
__global__ void k_count(const int* __restrict__ lei, int* __restrict__ counts) {
  int idx = blockIdx.x * 256 + threadIdx.x;
  int g = idx >> 11, e = idx & 2047;
  int d = lei[g * 4096 + 2048 + e];
  atomicAdd(&counts[g * 256 + d], 1);
}

__global__ void k_scan(const int* __restrict__ counts, int* __restrict__ rowptr,
                       int* __restrict__ pos) {
  int g = blockIdx.x, t = threadIdx.x;
  __shared__ int sc[256];
  int own = counts[g * 256 + t];
  sc[t] = own;
  __syncthreads();
  for (int off = 1; off < 256; off <<= 1) {
    int v = 0;
    if (t >= off) v = sc[t - off];
    __syncthreads();
    sc[t] += v;
    __syncthreads();
  }
  int val = g * 2048 + sc[t] - own; // exclusive
  rowptr[g * 256 + t] = val;
  pos[g * 256 + t] = val;
  if (g == B_G - 1 && t == 255) rowptr[B_G * 256] = B_G * 2048;
}

__global__ void k_fill(const int* __restrict__ lei, const int* __restrict__ ea,
                       int* __restrict__ pos, int* __restrict__ csr) {
  int idx = blockIdx.x * 256 + threadIdx.x;
  int g = idx >> 11, e = idx & 2047;
  int s = lei[g * 4096 + e];
  int d = lei[g * 4096 + 2048 + e];
  int eav = ea[g * 2048 + e];
  int slot = atomicAdd(&pos[g * 256 + d], 1);
  csr[slot] = s | (eav << 16);
}

// z = (1+eps)*(h+vn) + sum_{e->this} relu(h[src]+vn+eemb[ea])
// h = transform(src buffer): hsc? relu(x*hsc[c]+hsh[c]) : x*hmul
__global__ __launch_bounds__(256)
void k_agg(const float* __restrict__ H, float hmul,
           const float* __restrict__ hsc, const float* __restrict__ hsh,
           const float* __restrict__ vn, int vns,
           const float* __restrict__ eemb,
           const int* __restrict__ rowptr, const int* __restrict__ csr,
           const float* __restrict__ geps, int l, float* __restrict__ Z) {
  __shared__ float ee[16 * 256];
  for (int i = threadIdx.x; i < 4096; i += 256) ee[i] = eemb[i];
  __syncthreads();
  int lane = threadIdx.x & 63, w = threadIdx.x >> 6;
  int m = blockIdx.x * 4 + w;
  int g = m >> 8;
  int d = lane * 4;
  float eps1 = 1.0f + geps[l];
  float4 sc4 = make_float4(0, 0, 0, 0), sh4 = make_float4(0, 0, 0, 0);
  if (hsc) { sc4 = *(const float4*)&hsc[d]; sh4 = *(const float4*)&hsh[d]; }
  float4 vn4 = *(const float4*)&vn[(size_t)g * vns + d];
  int rp = rowptr[m], rp1 = rowptr[m + 1];
  float4 acc = make_float4(0, 0, 0, 0);
  int gbase = g << 8;
  for (int j = rp; j < rp1; j++) {
    int cw = csr[j];
    int src = cw & 0xFFFF, eav = cw >> 16;
    float4 h4 = *(const float4*)&H[(size_t)(gbase + src) * 256 + d];
    if (hsc) {
      h4.x = fmaf(h4.x, sc4.x, sh4.x); h4.y = fmaf(h4.y, sc4.y, sh4.y);
      h4.z = fmaf(h4.z, sc4.z, sh4.z); h4.w = fmaf(h4.w, sc4.w, sh4.w);
      h4.x = h4.x > 0 ? h4.x : 0; h4.y = h4.y > 0 ? h4.y : 0;
      h4.z = h4.z > 0 ? h4.z : 0; h4.w = h4.w > 0 ? h4.w : 0;
    } else {
      h4.x *= hmul; h4.y *= hmul; h4.z *= hmul; h4.w *= hmul;
    }
    const float4 e4 = *(const float4*)&ee[eav * 256 + d];
    float mx = h4.x + vn4.x + e4.x; float my = h4.y + vn4.y + e4.y;
    float mz = h4.z + vn4.z + e4.z; float mw = h4.w + vn4.w + e4.w;
    acc.x += mx > 0 ? mx : 0; acc.y += my > 0 ? my : 0;
    acc.z += mz > 0 ? mz : 0; acc.w += mw > 0 ? mw : 0;
  }
  float4 hs = *(const float4*)&H[(size_t)m * 256 + d];
  if (hsc) {
    hs.x = fmaf(hs.x, sc4.x, sh4.x); hs.y = fmaf(hs.y, sc4.y, sh4.y);
    hs.z = fmaf(hs.z, sc4.z, sh4.z); hs.w = fmaf(hs.w, sc4.w, sh4.w);
    hs.x = hs.x > 0 ? hs.x : 0; hs.y = hs.y > 0 ? hs.y : 0;
    hs.z = hs.z > 0 ? hs.z : 0; hs.w = hs.w > 0 ? hs.w : 0;
  } else {
    hs.x *= hmul; hs.y *= hmul; hs.z *= hmul; hs.w *= hmul;
  }
  float4 z4;
  z4.x = eps1 * (hs.x + vn4.x) + acc.x;
  z4.y = eps1 * (hs.y + vn4.y) + acc.y;
  z4.z = eps1 * (hs.z + vn4.z) + acc.z;
  z4.w = eps1 * (hs.w + vn4.w) + acc.w;
  *(float4*)&Z[(size_t)m * 256 + d] = z4;
}

// vn_out = relu(relu(vt@W1+B1)@W2+B2), vt = colsum_nodes(h) + 257*vn
__global__ __launch_bounds__(256)
void k_vn(const float* __restrict__ H, float hmul,
          const float* __restrict__ hsc, const float* __restrict__ hsh,
          const float* __restrict__ vn_in, int vns,
          const float* __restrict__ W1, const float* __restrict__ B1,
          const float* __restrict__ W2, const float* __restrict__ B2,
          float* __restrict__ vn_out) {
  int g = blockIdx.x, t = threadIdx.x;
  __shared__ float vt[256];
  __shared__ float u[512];
  float sc = 0, sh = 0;
  if (hsc) { sc = hsc[t]; sh = hsh[t]; }
  float s0 = 0, s1 = 0, s2 = 0, s3 = 0;
  for (int i = 0; i < 256; i += 4) {
    float v0 = H[(size_t)(g * 256 + i + 0) * 256 + t];
    float v1 = H[(size_t)(g * 256 + i + 1) * 256 + t];
    float v2 = H[(size_t)(g * 256 + i + 2) * 256 + t];
    float v3 = H[(size_t)(g * 256 + i + 3) * 256 + t];
    if (hsc) {
      v0 = fmaf(v0, sc, sh); v0 = v0 > 0 ? v0 : 0;
      v1 = fmaf(v1, sc, sh); v1 = v1 > 0 ? v1 : 0;
      v2 = fmaf(v2, sc, sh); v2 = v2 > 0 ? v2 : 0;
      v3 = fmaf(v3, sc, sh); v3 = v3 > 0 ? v3 : 0;
    } else { v0 *= hmul; v1 *= hmul; v2 *= hmul; v3 *= hmul; }
    s0 += v0; s1 += v1; s2 += v2; s3 += v3;
  }
  vt[t] = (s0 + s1) + (s2 + s3) + 257.0f * vn_in[(size_t)g * vns + t];
  __syncthreads();
  for (int o = t; o < 512; o += 256) {
    float a = B1[o];
    for (int k = 0; k < 256; k++) a = fmaf(vt[k], W1[k * 512 + o], a);
    u[o] = a > 0 ? a : 0;
  }
  __syncthreads();
  float a = B2[t];
  for (int k = 0; k < 512; k++) a = fmaf(u[k], W2[k * 256 + t], a);
  vn_out[g * 256 + t] = a > 0 ? a : 0;
}

// column sums + sumsq (atomic partials; dest pre-zeroed)
__global__ __launch_bounds__(256)
void k_colstats(const float* __restrict__ X, int NC,
                float* __restrict__ Ssum, float* __restrict__ Ssq) {
  int cl = threadIdx.x & 63, rl = threadIdx.x >> 6;
  int col = blockIdx.x * 64 + cl;
  int rbase = blockIdx.y * 1024;
  float s = 0, q = 0;
  for (int i = 0; i < 256; i++) {
    float v = X[(size_t)(rbase + rl + i * 4) * NC + col];
    s += v; q += v * v;
  }
  __shared__ float rs[4][64], rq[4][64];
  rs[rl][cl] = s; rq[rl][cl] = q;
  __syncthreads();
  if (rl == 0) {
    s = rs[0][cl] + rs[1][cl] + rs[2][cl] + rs[3][cl];
    q = rq[0][cl] + rq[1][cl] + rq[2][cl] + rq[3][cl];
    atomicAdd(&Ssum[col], s);
    atomicAdd(&Ssq[col], q);
  }
}

__global__ void k_bnfin(const float* __restrict__ Ssum, const float* __restrict__ Ssq,
                        const float* __restrict__ g, const float* __restrict__ b,
                        float* __restrict__ scale, float* __restrict__ shift,
                        int NC, float invN) {
  int c = blockIdx.x * 256 + threadIdx.x;
  if (c >= NC) return;
  float mu = Ssum[c] * invN;
  float var = Ssq[c] * invN - mu * mu;
  float rs = rsqrtf(var + 1e-5f);
  float s = rs * g[c];
  scale[c] = s;
  shift[c] = b[c] - mu * s;
}

// out = t2*sc[c]+sh[c] (final BN, JK='last', no relu)
__global__ void k_final(const float* __restrict__ T2, const float* __restrict__ sc,
                        const float* __restrict__ sh, float* __restrict__ out) {
  int i = blockIdx.x * 256 + threadIdx.x; // 2097152 float4s
  int c4 = (i & 63) * 4;
  float4 v = *(const float4*)&T2[(size_t)i * 4];
  float4 s4 = *(const float4*)&sc[c4];
  float4 h4 = *(const float4*)&sh[c4];
  v.x = fmaf(v.x, s4.x, h4.x); v.y = fmaf(v.y, s4.y, h4.y);
  v.z = fmaf(v.z, s4.z, h4.z); v.w = fmaf(v.w, s4.w, h4.w);
  *(float4*)&out[(size_t)i * 4] = v;
}

extern "C" void kernel_launch(void* const* d_in, const int* in_sizes, int n_in,
                              void* d_out, int out_size, void* d_ws, size_t ws_size,
                              hipStream_t stream) {
  (void)in_sizes; (void)n_in; (void)out_size; (void)ws_size;
  const int*   atom_idx = (const int*)d_in[0];
  const int*   lei      = (const int*)d_in[1];
  const int*   eattr    = (const int*)d_in[2];
  const float* atom_emb = (const float*)d_in[4];
  const float* bemb_h   = (const float*)d_in[5];
  const float* elw      = (const float*)d_in[6];
  const float* elb      = (const float*)d_in[7];
  const float* bemb_l   = (const float*)d_in[8];
  const float* geps     = (const float*)d_in[9];
  const float* mw1      = (const float*)d_in[10];
  const float* mb1      = (const float*)d_in[11];
  const float* mbng     = (const float*)d_in[12];
  const float* mbnb     = (const float*)d_in[13];
  const float* mw2      = (const float*)d_in[14];
  const float* mb2      = (const float*)d_in[15];
  const float* obng     = (const float*)d_in[16];
  const float* obnb     = (const float*)d_in[17];
  const float* vne      = (const float*)d_in[18];
  const float* vw1      = (const float*)d_in[19];
  const float* vb1      = (const float*)d_in[20];
  const float* vw2      = (const float*)d_in[21];
  const float* vb2      = (const float*)d_in[22];
  float* out = (float*)d_out;

  // ws layout (33.55MB units): A_, X0T, X1T, YT, Z_, SM(tail)
  // aliases: T2=A_ (adjacency dead after prop); H0=X0T (free after prop);
  // T1=[X1T,YT] contiguous 67MB (both dead after prop+transpose);
  // PACKED=Z_ (dead before layer-0 k_agg).
  float* W   = (float*)d_ws;
  float* A_  = W;
  float* X0T = W + (size_t)FBUF;
  float* X1T = W + (size_t)2 * FBUF;
  float* YT  = W + (size_t)3 * FBUF;
  float* Z_  = W + (size_t)4 * FBUF;
  float* SM  = W + (size_t)5 * FBUF;
  float* EWT = SM;             // 16
  float* S1S = SM + 256;       // 512
  float* S1Q = SM + 768;       // 512
  float* S2S = SM + 1280;      // 256
  float* S2Q = SM + 1536;      // 256
  float* SC1 = SM + 1792;      // 512
  float* SH1 = SM + 2304;      // 512
  float* SC2 = SM + 2816;      // 256
  float* SH2 = SM + 3072;      // 256
  float* VNA = SM + 3328;      // 32768
  float* VNB = SM + 36096;     // 32768
  int* ROWPTR = (int*)(SM + 68864);  // 32772
  int* POS    = ROWPTR + 32772;      // 32768
  int* COUNTS = POS + 32768;         // 32768
  int* CSR    = COUNTS + 32768;      // 262144
  float* W1T  = SM + 429568;         // 5*512*256 = 655360
  float* W2T  = SM + 1084928;        // 5*256*512 = 655360
  float* T1 = X1T;   // [32768][512] spans X1T+YT
  float* T2 = A_;
  float* H0 = X0T;
  int* PACKED = (int*)Z_;

  // ---- stage 1: dense learned-adjacency propagation (transposed space) ----
  k_zero<<<8192, 256, 0, stream>>>((uint4*)A_, 2097152);
  k_zero<<<8192, 256, 0, stream>>>((uint4*)PACKED, 2097152);
  k_zero<<<32, 256, 0, stream>>>((uint4*)COUNTS, 8192);
  k_ewtbl<<<1, 64, 0, stream>>>(bemb_h, elw, elb, EWT);
  k_pack_adj<<<NEDGE / 256, 256, 0, stream>>>(lei, eattr, PACKED);
  k_unpack_adj<<<32768, 256, 0, stream>>>(PACKED, EWT, A_);
  k_addeye<<<NNODE / 256, 256, 0, stream>>>(A_);
  k_degnorm<<<B_G, 256, 0, stream>>>(A_);
  // weight pre-transposes (independent; small)
  k_transp<<<dim3(8, 4, 5), 256, 0, stream>>>(mw1, W1T, 256, 512, 131072, 131072, 1.0f);
  k_transp<<<dim3(4, 8, 5), 256, 0, stream>>>(mw2, W2T, 512, 256, 131072, 131072, 1.0f);
  k_feaT<<<32768, 256, 0, stream>>>(atom_idx, atom_emb, X0T, YT);
  // order=3: Xt_next = Xt @ A^T (== (A@X)^T), Yt accumulates
  k_mgemm<<<dim3(2, 2, B_G), 256, 0, stream>>>(X0T, A_, nullptr, X1T, YT,
      256, 256, 65536, 65536, 65536, nullptr, nullptr);
  k_mgemm<<<dim3(2, 2, B_G), 256, 0, stream>>>(X1T, A_, nullptr, X0T, YT,
      256, 256, 65536, 65536, 65536, nullptr, nullptr);
  k_mgemm<<<dim3(2, 2, B_G), 256, 0, stream>>>(X0T, A_, nullptr, X1T, YT,
      256, 256, 65536, 65536, 65536, nullptr, nullptr);
  // H0[n][e] = 0.25 * YT[e][n]
  k_transp<<<dim3(4, 4, B_G), 256, 0, stream>>>(YT, H0, 256, 256, 65536, 65536, 0.25f);

  // ---- CSR (once; edges invariant across layers) ----
  k_count<<<NEDGE / 256, 256, 0, stream>>>(lei, COUNTS);
  k_scan<<<B_G, 256, 0, stream>>>(COUNTS, ROWPTR, POS);
  k_fill<<<NEDGE / 256, 256, 0, stream>>>(lei, eattr, POS, CSR);

  // ---- GIN + virtual-node stack ----
  const float* vn_cur = vne; int vns = 0;   // layer0 vn = vn_emb broadcast
  float* vn_next = VNA;
  for (int l = 0; l < NL; l++) {
    const float* hsrc = (l == 0) ? H0 : T2;
    const float* hsc  = (l == 0) ? nullptr : SC2;
    const float* hsh  = (l == 0) ? nullptr : SH2;
    k_agg<<<NNODE / 4, 256, 0, stream>>>(hsrc, 1.0f, hsc, hsh, vn_cur, vns,
        bemb_l + (size_t)l * 16 * EMB, ROWPTR, CSR, geps, l, Z_);
    if (l < NL - 1)
      k_vn<<<B_G, 256, 0, stream>>>(hsrc, 1.0f, hsc, hsh, vn_cur, vns,
          vw1 + (size_t)l * EMB * 512, vb1 + (size_t)l * 512,
          vw2 + (size_t)l * 512 * EMB, vb2 + (size_t)l * EMB, vn_next);
    k_zero<<<2, 256, 0, stream>>>((uint4*)S1S, 384); // S1S,S1Q,S2S,S2Q
    k_mgemm<<<dim3(4, 256, 1), 256, 0, stream>>>(Z_, W1T + (size_t)l * 131072,
        mb1 + (size_t)l * 512, T1, nullptr, 256, 512, 0, 0, 0, nullptr, nullptr);
    k_colstats<<<dim3(8, 32), 256, 0, stream>>>(T1, 512, S1S, S1Q);
    k_bnfin<<<2, 256, 0, stream>>>(S1S, S1Q, mbng + (size_t)l * 512,
        mbnb + (size_t)l * 512, SC1, SH1, 512, 1.0f / NNODE);
    k_mgemm<<<dim3(2, 256, 1), 256, 0, stream>>>(T1, W2T + (size_t)l * 131072,
        mb2 + (size_t)l * 256, T2, nullptr, 512, 256, 0, 0, 0, SC1, SH1);
    k_colstats<<<dim3(4, 32), 256, 0, stream>>>(T2, 256, S2S, S2Q);
    k_bnfin<<<1, 256, 0, stream>>>(S2S, S2Q, obng + (size_t)l * EMB,
        obnb + (size_t)l * EMB, SC2, SH2, 256, 1.0f / NNODE);
    if (l < NL - 1) {
      vn_cur = vn_next; vns = EMB;
      vn_next = (vn_next == VNA) ? VNB : VNA;
    }
  }
  k_final<<<8192, 256, 0, stream>>>(T2, SC2, SH2, out);
}

// Round 4
// 1409.242 us; speedup vs baseline: 1.7944x; 1.2558x over previous
//
#include <hip/hip_runtime.h>
#include <math.h>

// GNN_node_Virtualnode: B=128 graphs, 256 nodes/graph, 2048 edges/graph,
// emb=256, 5 GIN layers + virtual node, learned dense-adjacency propagation.
// Round 3: MLP GEMMs take pre-split bf16 hi/lo operands via global_load_lds
// (m97 structure); column-stats fused into GEMM epilogue; BN+relu+resplit as
// an in-place elementwise pass. Prop keeps the validated fp32-split kernel.

#define B_G   128
#define NPG   256
#define EPG   2048
#define EMB   256
#define NL    5
#define NNODE (B_G*NPG)   // 32768
#define NEDGE (B_G*EPG)   // 262144
#define FBUF  8388608     // floats per 33.55MB buffer

typedef __attribute__((ext_vector_type(8))) short bf16x8;
typedef __attribute__((ext_vector_type(4))) float f32x4;

// ---------------- helpers ----------------
__device__ __forceinline__ void split1(float x, unsigned short& h, unsigned short& l) {
  // round-to-nearest-even bf16 hi, then bf16(residual)
  unsigned u = __builtin_bit_cast(unsigned, x);
  unsigned hr = u + 0x7FFFu + ((u >> 16) & 1u);
  h = (unsigned short)(hr >> 16);
  float hf = __builtin_bit_cast(float, hr & 0xFFFF0000u);
  float r = x - hf;
  unsigned v = __builtin_bit_cast(unsigned, r);
  unsigned lr = v + 0x7FFFu + ((v >> 16) & 1u);
  l = (unsigned short)(lr >> 16);
}

__device__ __forceinline__ float bdec(unsigned short h) {
  return __builtin_bit_cast(float, (unsigned)h << 16);
}

__device__ __forceinline__ void gload16(unsigned short* lds, const unsigned short* g) {
  // async global->LDS, 16B/lane; LDS dest = wave-uniform base + lane*16
  __builtin_amdgcn_global_load_lds(
      (const __attribute__((address_space(1))) unsigned int*)g,
      (__attribute__((address_space(3))) unsigned int*)lds, 16, 0, 0);
}

__global__ void k_zero(uint4* p, int n16) {
  int i = blockIdx.x * 256 + threadIdx.x;
  if (i < n16) p[i] = make_uint4(0, 0, 0, 0);
}

// 16-entry sigmoid edge-weight table: 16 waves, one per bond value
__global__ void k_ewtbl(const float* __restrict__ bh, const float* __restrict__ w,
                        const float* __restrict__ b, float* __restrict__ tbl) {
  int v = threadIdx.x >> 6, t = threadIdx.x & 63;
  float p = bh[v * 64 + t] * w[t];
  for (int off = 32; off; off >>= 1) p += __shfl_down(p, off, 64);
  if (t == 0) tbl[v] = 1.0f / (1.0f + expf(-(p + b[0])));
}

// Deterministic duplicate resolution: last edge (max e) wins.
__global__ void k_pack_adj(const int* __restrict__ lei, const int* __restrict__ ea,
                           int* __restrict__ packed) {
  int idx = blockIdx.x * 256 + threadIdx.x;       // NEDGE
  int g = idx >> 11, e = idx & 2047;
  int s = lei[g * 4096 + e];
  int d = lei[g * 4096 + 2048 + e];
  int v = ((e + 1) << 4) | ea[g * 2048 + e];
  atomicMax(&packed[g * 65536 + s * 256 + d], v);
}

__global__ void k_unpack_adj(const int* __restrict__ packed,
                             const float* __restrict__ tbl, float* __restrict__ adj) {
  int idx = blockIdx.x * 256 + threadIdx.x;       // 8388608
  int v = packed[idx];
  adj[idx] = v ? tbl[v & 15] : 0.0f;
}

__global__ void k_addeye(float* __restrict__ adj) {
  int idx = blockIdx.x * 256 + threadIdx.x;       // NNODE
  int g = idx >> 8, i = idx & 255;
  adj[g * 65536 + i * 257] += 1.0f;
}

// A[i][j] = colsum(i)^-1/2 * adj[i][j] * rowsum(j)^-1/2  (in place)
__global__ __launch_bounds__(256)
void k_degnorm(float* __restrict__ adj) {
  int g = blockIdx.x, t = threadIdx.x;
  float* Ag = adj + (size_t)g * 65536;
  __shared__ float cs[256];
  float s0 = 0, s1 = 0, s2 = 0, s3 = 0;
  for (int i = 0; i < 256; i += 4) {
    s0 += Ag[(i + 0) * 256 + t]; s1 += Ag[(i + 1) * 256 + t];
    s2 += Ag[(i + 2) * 256 + t]; s3 += Ag[(i + 3) * 256 + t];
  }
  cs[t] = rsqrtf((s0 + s1) + (s2 + s3));          // colsum(t)^-1/2
  float4 r0 = make_float4(0, 0, 0, 0), r1 = r0, r2 = r0, r3 = r0;
  const float4* A4 = (const float4*)(Ag + t * 256);
  for (int j = 0; j < 64; j += 4) {
    float4 v0 = A4[j], v1 = A4[j + 1], v2 = A4[j + 2], v3 = A4[j + 3];
    r0.x += v0.x + v0.y; r0.y += v0.z + v0.w;
    r1.x += v1.x + v1.y; r1.y += v1.z + v1.w;
    r2.x += v2.x + v2.y; r2.y += v2.z + v2.w;
    r3.x += v3.x + v3.y; r3.y += v3.z + v3.w;
  }
  float rc = rsqrtf((r0.x + r0.y) + (r1.x + r1.y) + (r2.x + r2.y) + (r3.x + r3.y));
  __syncthreads();
  for (int i = 0; i < 256; i++) Ag[i * 256 + t] = cs[i] * Ag[i * 256 + t] * rc;
}

// transposed fea gather: X0t[g][e][n] = Yt[g][e][n] = atom_emb[aidx[g*256+n]][e]
__global__ void k_feaT(const int* __restrict__ aidx, const float* __restrict__ aemb,
                       float* __restrict__ X0t, float* __restrict__ Yt) {
  int i = blockIdx.x * 256 + threadIdx.x;          // 8388608
  int g = i >> 16, e = (i >> 8) & 255, n = i & 255;
  int av = aidx[g * 256 + n];
  float v = aemb[av * 256 + e];
  X0t[i] = v; Yt[i] = v;
}

// generic LDS-tiled transpose: dst[z][N][K] = scale * src[z][K][N]
__global__ __launch_bounds__(256)
void k_transp(const float* __restrict__ src, float* __restrict__ dst,
              int K, int N, long ss, long sd, float scale) {
  __shared__ float tl[64][65];
  src += (size_t)blockIdx.z * ss; dst += (size_t)blockIdx.z * sd;
  int n0 = blockIdx.x * 64, k0 = blockIdx.y * 64;
  int t = threadIdx.x;
  int c = (t & 15) * 4, r = t >> 4;
#pragma unroll
  for (int p = 0; p < 4; p++) {
    int rr = r + p * 16;
    float4 v = *(const float4*)&src[(size_t)(k0 + rr) * N + n0 + c];
    tl[rr][c] = v.x; tl[rr][c + 1] = v.y; tl[rr][c + 2] = v.z; tl[rr][c + 3] = v.w;
  }
  __syncthreads();
#pragma unroll
  for (int p = 0; p < 4; p++) {
    int rr = r + p * 16;
    float4 o;
    o.x = tl[c][rr] * scale;     o.y = tl[c + 1][rr] * scale;
    o.z = tl[c + 2][rr] * scale; o.w = tl[c + 3][rr] * scale;
    *(float4*)&dst[(size_t)(n0 + rr) * K + k0 + c] = o;
  }
}

// fused transpose + hi/lo split: dh/dl[z][N][K] = split(src[z][K][N])
__global__ __launch_bounds__(256)
void k_wtsplit(const float* __restrict__ src, unsigned short* __restrict__ dh,
               unsigned short* __restrict__ dl, int K, int N, long ss, long sd) {
  __shared__ float tl[64][65];
  src += (size_t)blockIdx.z * ss;
  dh += (size_t)blockIdx.z * sd; dl += (size_t)blockIdx.z * sd;
  int n0 = blockIdx.x * 64, k0 = blockIdx.y * 64;
  int t = threadIdx.x;
  int c = (t & 15) * 4, r = t >> 4;
#pragma unroll
  for (int p = 0; p < 4; p++) {
    int rr = r + p * 16;
    float4 v = *(const float4*)&src[(size_t)(k0 + rr) * N + n0 + c];
    tl[rr][c] = v.x; tl[rr][c + 1] = v.y; tl[rr][c + 2] = v.z; tl[rr][c + 3] = v.w;
  }
  __syncthreads();
#pragma unroll
  for (int p = 0; p < 4; p++) {
    int rr = r + p * 16;
    ushort4 hh, ll;
    split1(tl[c][rr],     hh.x, ll.x);
    split1(tl[c + 1][rr], hh.y, ll.y);
    split1(tl[c + 2][rr], hh.z, ll.z);
    split1(tl[c + 3][rr], hh.w, ll.w);
    size_t o = (size_t)(n0 + rr) * K + k0 + c;
    *(ushort4*)&dh[o] = hh; *(ushort4*)&dl[o] = ll;
  }
}

// ---- prop GEMM (fp32 inputs, in-kernel split; validated R2 kernel) ----
// C[z][M][N] = A[z][M][K] @ Bt[z][N][K]^T ; optional Yacc += C.
__global__ __launch_bounds__(256, 2)
void k_mgemm(const float* __restrict__ A, const float* __restrict__ Bt,
             float* __restrict__ C, float* __restrict__ Yacc, int K, int N,
             long sA, long sBt, long sC) {
  __shared__ alignas(16) unsigned short Ah[128 * 64], Al[128 * 64];
  __shared__ alignas(16) unsigned short Bh[128 * 64], Bl[128 * 64];
  int z = blockIdx.z;
  A += (size_t)z * sA; Bt += (size_t)z * sBt; C += (size_t)z * sC;
  float* Yp = Yacc ? Yacc + (size_t)z * sC : nullptr;
  int rowbase = blockIdx.y * 128, colbase = blockIdx.x * 128;
  int t = threadIdx.x, l = t & 63, w = t >> 6;
  int wr = w >> 1, wc = w & 1;
  f32x4 acc[4][4];
#pragma unroll
  for (int i = 0; i < 4; i++)
#pragma unroll
    for (int j = 0; j < 4; j++) acc[i][j] = (f32x4){0, 0, 0, 0};

  for (int k0 = 0; k0 < K; k0 += 64) {
    __syncthreads();
    for (int p = 0; p < 8; p++) {
      int flat = p * 256 + t;                    // 0..2047
      int r = flat >> 4, kq = (flat & 15) * 4;   // row 0..127, k-quad
      float4 va = *(const float4*)&A[(size_t)(rowbase + r) * K + k0 + kq];
      int off = ((r * 128 + kq * 2) ^ ((r & 7) << 4)) >> 1;  // short index
      ushort4 hh, ll;
      split1(va.x, hh.x, ll.x); split1(va.y, hh.y, ll.y);
      split1(va.z, hh.z, ll.z); split1(va.w, hh.w, ll.w);
      *(ushort4*)&Ah[off] = hh; *(ushort4*)&Al[off] = ll;
      float4 vb = *(const float4*)&Bt[(size_t)(colbase + r) * K + k0 + kq];
      split1(vb.x, hh.x, ll.x); split1(vb.y, hh.y, ll.y);
      split1(vb.z, hh.z, ll.z); split1(vb.w, hh.w, ll.w);
      *(ushort4*)&Bh[off] = hh; *(ushort4*)&Bl[off] = ll;
    }
    __syncthreads();
#pragma unroll
    for (int ks = 0; ks < 2; ks++) {
      bf16x8 ah[4], al_[4], bh[4], bl[4];
#pragma unroll
      for (int fm = 0; fm < 4; fm++) {
        int r = wr * 64 + fm * 16 + (l & 15);
        int off = (r * 64 + ks * 32 + (l >> 4) * 8) ^ ((r & 7) << 3);
        ah[fm] = *(const bf16x8*)&Ah[off];
        al_[fm] = *(const bf16x8*)&Al[off];
      }
#pragma unroll
      for (int fn = 0; fn < 4; fn++) {
        int c = wc * 64 + fn * 16 + (l & 15);
        int off = (c * 64 + ks * 32 + (l >> 4) * 8) ^ ((c & 7) << 3);
        bh[fn] = *(const bf16x8*)&Bh[off];
        bl[fn] = *(const bf16x8*)&Bl[off];
      }
#pragma unroll
      for (int fm = 0; fm < 4; fm++)
#pragma unroll
        for (int fn = 0; fn < 4; fn++) {
          acc[fm][fn] = __builtin_amdgcn_mfma_f32_16x16x32_bf16(ah[fm], bh[fn], acc[fm][fn], 0, 0, 0);
          acc[fm][fn] = __builtin_amdgcn_mfma_f32_16x16x32_bf16(ah[fm], bl[fn], acc[fm][fn], 0, 0, 0);
          acc[fm][fn] = __builtin_amdgcn_mfma_f32_16x16x32_bf16(al_[fm], bh[fn], acc[fm][fn], 0, 0, 0);
        }
    }
  }
#pragma unroll
  for (int fm = 0; fm < 4; fm++)
#pragma unroll
    for (int r4 = 0; r4 < 4; r4++) {
      int row = rowbase + wr * 64 + fm * 16 + (l >> 4) * 4 + r4;
#pragma unroll
      for (int fn = 0; fn < 4; fn++) {
        int col = colbase + wc * 64 + fn * 16 + (l & 15);
        float v = acc[fm][fn][r4];
        size_t idx = (size_t)row * N + col;
        if (Yp) Yp[idx] += v;
        C[idx] = v;
      }
    }
}

// ---- MLP GEMM: pre-split bf16 hi/lo operands, global_load_lds staging ----
// C = (Ah+Al) @ (Bh+Bl)^T + bias (3-term); A[M][K], Bt[N][K] as pairs.
// Output: fp32 Cf OR bf16 pair (Ch,Cl). Optional fused column sum/sumsq.
__global__ __launch_bounds__(256, 2)
void k_bgemm(const unsigned short* __restrict__ Ah_g, const unsigned short* __restrict__ Al_g,
             const unsigned short* __restrict__ Bh_g, const unsigned short* __restrict__ Bl_g,
             const float* __restrict__ bias, float* __restrict__ Cf,
             unsigned short* __restrict__ Ch, unsigned short* __restrict__ Cl,
             float* __restrict__ Ssum, float* __restrict__ Ssq, int K, int N) {
  __shared__ alignas(16) unsigned short Ah[128 * 64], Al[128 * 64];
  __shared__ alignas(16) unsigned short Bh[128 * 64], Bl[128 * 64];
  int rowbase = blockIdx.y * 128, colbase = blockIdx.x * 128;
  int t = threadIdx.x, l = t & 63, wid = t >> 6;
  int wr = wid >> 1, wc = wid & 1;
  int r8 = l >> 3, cb = (l & 7) * 8;               // staging lane -> (row, col)
  f32x4 acc[4][4];
#pragma unroll
  for (int i = 0; i < 4; i++)
#pragma unroll
    for (int j = 0; j < 4; j++) acc[i][j] = (f32x4){0, 0, 0, 0};

  for (int k0 = 0; k0 < K; k0 += 64) {
    __syncthreads();                               // prior readers done
#pragma unroll
    for (int i = 0; i < 4; i++) {
      int chunk = wid * 4 + i;                     // 0..15 -> 8 rows each
      int row = chunk * 8 + r8;
      size_t goA = (size_t)(rowbase + row) * K + k0 + cb;
      size_t goB = (size_t)(colbase + row) * K + k0 + cb;
      gload16(Ah + chunk * 512, Ah_g + goA);
      gload16(Al + chunk * 512, Al_g + goA);
      gload16(Bh + chunk * 512, Bh_g + goB);
      gload16(Bl + chunk * 512, Bl_g + goB);
    }
    __syncthreads();                               // vmcnt(0) drain + barrier
#pragma unroll
    for (int ks = 0; ks < 2; ks++) {
      bf16x8 ah[4], al_[4], bh[4], bl[4];
#pragma unroll
      for (int fm = 0; fm < 4; fm++) {
        int r = wr * 64 + fm * 16 + (l & 15);
        ah[fm]  = *(const bf16x8*)&Ah[r * 64 + ks * 32 + (l >> 4) * 8];
        al_[fm] = *(const bf16x8*)&Al[r * 64 + ks * 32 + (l >> 4) * 8];
      }
#pragma unroll
      for (int fn = 0; fn < 4; fn++) {
        int c = wc * 64 + fn * 16 + (l & 15);
        bh[fn] = *(const bf16x8*)&Bh[c * 64 + ks * 32 + (l >> 4) * 8];
        bl[fn] = *(const bf16x8*)&Bl[c * 64 + ks * 32 + (l >> 4) * 8];
      }
#pragma unroll
      for (int fm = 0; fm < 4; fm++)
#pragma unroll
        for (int fn = 0; fn < 4; fn++) {
          acc[fm][fn] = __builtin_amdgcn_mfma_f32_16x16x32_bf16(ah[fm], bh[fn], acc[fm][fn], 0, 0, 0);
          acc[fm][fn] = __builtin_amdgcn_mfma_f32_16x16x32_bf16(ah[fm], bl[fn], acc[fm][fn], 0, 0, 0);
          acc[fm][fn] = __builtin_amdgcn_mfma_f32_16x16x32_bf16(al_[fm], bh[fn], acc[fm][fn], 0, 0, 0);
        }
    }
  }
  __syncthreads();
  float bi[4], scoll[4] = {0, 0, 0, 0}, qcoll[4] = {0, 0, 0, 0};
#pragma unroll
  for (int fn = 0; fn < 4; fn++)
    bi[fn] = bias ? bias[colbase + wc * 64 + fn * 16 + (l & 15)] : 0.0f;
#pragma unroll
  for (int fm = 0; fm < 4; fm++)
#pragma unroll
    for (int r4 = 0; r4 < 4; r4++) {
      int row = rowbase + wr * 64 + fm * 16 + (l >> 4) * 4 + r4;
#pragma unroll
      for (int fn = 0; fn < 4; fn++) {
        int col = colbase + wc * 64 + fn * 16 + (l & 15);
        float v = acc[fm][fn][r4] + bi[fn];
        size_t idx = (size_t)row * N + col;
        if (Cf) Cf[idx] = v;
        if (Ch) { unsigned short hh, ll; split1(v, hh, ll); Ch[idx] = hh; Cl[idx] = ll; }
        scoll[fn] += v; qcoll[fn] += v * v;
      }
    }
  if (Ssum) {
    float* scr = (float*)Ah;                       // 256 floats scratch
    scr[t] = 0.0f;
    __syncthreads();
#pragma unroll
    for (int fn = 0; fn < 4; fn++) {
      int cl_ = wc * 64 + fn * 16 + (l & 15);
      atomicAdd(&scr[cl_ * 2], scoll[fn]);
      atomicAdd(&scr[cl_ * 2 + 1], qcoll[fn]);
    }
    __syncthreads();
    if (t < 128) {
      atomicAdd(&Ssum[colbase + t], scr[t * 2]);
      atomicAdd(&Ssq[colbase + t], scr[t * 2 + 1]);
    }
  }
}

// in-place BN(+relu) on T1 hi/lo pairs; BN1 finalize fused (reads raw stats)
__global__ void k_bnsplit(unsigned short* __restrict__ Th, unsigned short* __restrict__ Tl,
                          const float* __restrict__ Ssum, const float* __restrict__ Ssq,
                          const float* __restrict__ g, const float* __restrict__ b) {
  size_t i = (size_t)blockIdx.x * 256 + threadIdx.x;  // 4.19M threads x4 elems
  int c4 = ((int)i & 127) * 4;
  ushort4 h4 = *(ushort4*)&Th[i * 4];
  ushort4 l4 = *(ushort4*)&Tl[i * 4];
  float4 ss = *(const float4*)&Ssum[c4], qq = *(const float4*)&Ssq[c4];
  float4 gg = *(const float4*)&g[c4],    bb = *(const float4*)&b[c4];
  const float invN = 1.0f / 32768.0f;
  float x, mu, var, sc, sh;
#define BNS(cmp) \
  mu = ss.cmp * invN; var = qq.cmp * invN - mu * mu; \
  sc = rsqrtf(var + 1e-5f) * gg.cmp; sh = bb.cmp - mu * sc; \
  x = bdec(h4.cmp) + bdec(l4.cmp); x = fmaf(x, sc, sh); x = x > 0 ? x : 0; \
  split1(x, h4.cmp, l4.cmp);
  BNS(x) BNS(y) BNS(z) BNS(w)
#undef BNS
  *(ushort4*)&Th[i * 4] = h4;
  *(ushort4*)&Tl[i * 4] = l4;
}

// ---- CSR build (edge structure is layer-invariant; built once) ----
__global__ void k_count(const int* __restrict__ lei, int* __restrict__ counts) {
  int idx = blockIdx.x * 256 + threadIdx.x;
  int g = idx >> 11, e = idx & 2047;
  int d = lei[g * 4096 + 2048 + e];
  atomicAdd(&counts[g * 256 + d], 1);
}

__global__ void k_scan(const int* __restrict__ counts, int* __restrict__ rowptr,
                       int* __restrict__ pos) {
  int g = blockIdx.x, t = threadIdx.x;
  __shared__ int sc[256];
  int own = counts[g * 256 + t];
  sc[t] = own;
  __syncthreads();
  for (int off = 1; off < 256; off <<= 1) {
    int v = 0;
    if (t >= off) v = sc[t - off];
    __syncthreads();
    sc[t] += v;
    __syncthreads();
  }
  int val = g * 2048 + sc[t] - own; // exclusive
  rowptr[g * 256 + t] = val;
  pos[g * 256 + t] = val;
  if (g == B_G - 1 && t == 255) rowptr[B_G * 256] = B_G * 2048;
}

__global__ void k_fill(const int* __restrict__ lei, const int* __restrict__ ea,
                       int* __restrict__ pos, int* __restrict__ csr) {
  int idx = blockIdx.x * 256 + threadIdx.x;
  int g = idx >> 11, e = idx & 2047;
  int s = lei[g * 4096 + e];
  int d = lei[g * 4096 + 2048 + e];
  int eav = ea[g * 2048 + e];
  int slot = atomicAdd(&pos[g * 256 + d], 1);
  csr[slot] = s | (eav << 16);
}

// z = (1+eps)*(h+vn) + sum_{e->this} relu(h[src]+vn+eemb[ea]); out as bf16 pair
__global__ __launch_bounds__(256)
void k_agg(const float* __restrict__ H,
           const float* __restrict__ hsc, const float* __restrict__ hsh,
           const float* __restrict__ vn, int vns,
           const float* __restrict__ eemb,
           const int* __restrict__ rowptr, const int* __restrict__ csr,
           const float* __restrict__ geps, int l,
           unsigned short* __restrict__ Zh, unsigned short* __restrict__ Zl) {
  __shared__ float ee[16 * 256];
  for (int i = threadIdx.x; i < 4096; i += 256) ee[i] = eemb[i];
  __syncthreads();
  int lane = threadIdx.x & 63, w = threadIdx.x >> 6;
  int m = blockIdx.x * 4 + w;
  int g = m >> 8;
  int d = lane * 4;
  float eps1 = 1.0f + geps[l];
  float4 sc4 = make_float4(0, 0, 0, 0), sh4 = make_float4(0, 0, 0, 0);
  if (hsc) { sc4 = *(const float4*)&hsc[d]; sh4 = *(const float4*)&hsh[d]; }
  float4 vn4 = *(const float4*)&vn[(size_t)g * vns + d];
  int rp = rowptr[m], rp1 = rowptr[m + 1];
  float4 acc = make_float4(0, 0, 0, 0);
  int gbase = g << 8;
  for (int j = rp; j < rp1; j++) {
    int cw = csr[j];
    int src = cw & 0xFFFF, eav = cw >> 16;
    float4 h4 = *(const float4*)&H[(size_t)(gbase + src) * 256 + d];
    if (hsc) {
      h4.x = fmaf(h4.x, sc4.x, sh4.x); h4.y = fmaf(h4.y, sc4.y, sh4.y);
      h4.z = fmaf(h4.z, sc4.z, sh4.z); h4.w = fmaf(h4.w, sc4.w, sh4.w);
      h4.x = h4.x > 0 ? h4.x : 0; h4.y = h4.y > 0 ? h4.y : 0;
      h4.z = h4.z > 0 ? h4.z : 0; h4.w = h4.w > 0 ? h4.w : 0;
    }
    const float4 e4 = *(const float4*)&ee[eav * 256 + d];
    float mx = h4.x + vn4.x + e4.x; float my = h4.y + vn4.y + e4.y;
    float mz = h4.z + vn4.z + e4.z; float mw = h4.w + vn4.w + e4.w;
    acc.x += mx > 0 ? mx : 0; acc.y += my > 0 ? my : 0;
    acc.z += mz > 0 ? mz : 0; acc.w += mw > 0 ? mw : 0;
  }
  float4 hs = *(const float4*)&H[(size_t)m * 256 + d];
  if (hsc) {
    hs.x = fmaf(hs.x, sc4.x, sh4.x); hs.y = fmaf(hs.y, sc4.y, sh4.y);
    hs.z = fmaf(hs.z, sc4.z, sh4.z); hs.w = fmaf(hs.w, sc4.w, sh4.w);
    hs.x = hs.x > 0 ? hs.x : 0; hs.y = hs.y > 0 ? hs.y : 0;
    hs.z = hs.z > 0 ? hs.z : 0; hs.w = hs.w > 0 ? hs.w : 0;
  }
  float4 z4;
  z4.x = eps1 * (hs.x + vn4.x) + acc.x;
  z4.y = eps1 * (hs.y + vn4.y) + acc.y;
  z4.z = eps1 * (hs.z + vn4.z) + acc.z;
  z4.w = eps1 * (hs.w + vn4.w) + acc.w;
  ushort4 hh, ll;
  split1(z4.x, hh.x, ll.x); split1(z4.y, hh.y, ll.y);
  split1(z4.z, hh.z, ll.z); split1(z4.w, hh.w, ll.w);
  *(ushort4*)&Zh[(size_t)m * 256 + d] = hh;
  *(ushort4*)&Zl[(size_t)m * 256 + d] = ll;
}

// vn_out = relu(relu(vt@W1+B1)@W2+B2), vt = colsum_nodes(h) + 257*vn
__global__ __launch_bounds__(256)
void k_vn(const float* __restrict__ H,
          const float* __restrict__ hsc, const float* __restrict__ hsh,
          const float* __restrict__ vn_in, int vns,
          const float* __restrict__ W1, const float* __restrict__ B1,
          const float* __restrict__ W2, const float* __restrict__ B2,
          float* __restrict__ vn_out) {
  int g = blockIdx.x, t = threadIdx.x;
  __shared__ float vt[256];
  __shared__ float u[512];
  float sc = 0, sh = 0;
  if (hsc) { sc = hsc[t]; sh = hsh[t]; }
  float s0 = 0, s1 = 0, s2 = 0, s3 = 0;
  for (int i = 0; i < 256; i += 4) {
    float v0 = H[(size_t)(g * 256 + i + 0) * 256 + t];
    float v1 = H[(size_t)(g * 256 + i + 1) * 256 + t];
    float v2 = H[(size_t)(g * 256 + i + 2) * 256 + t];
    float v3 = H[(size_t)(g * 256 + i + 3) * 256 + t];
    if (hsc) {
      v0 = fmaf(v0, sc, sh); v0 = v0 > 0 ? v0 : 0;
      v1 = fmaf(v1, sc, sh); v1 = v1 > 0 ? v1 : 0;
      v2 = fmaf(v2, sc, sh); v2 = v2 > 0 ? v2 : 0;
      v3 = fmaf(v3, sc, sh); v3 = v3 > 0 ? v3 : 0;
    }
    s0 += v0; s1 += v1; s2 += v2; s3 += v3;
  }
  vt[t] = (s0 + s1) + (s2 + s3) + 257.0f * vn_in[(size_t)g * vns + t];
  __syncthreads();
  for (int o = t; o < 512; o += 256) {
    float a = B1[o];
    for (int k = 0; k < 256; k++) a = fmaf(vt[k], W1[k * 512 + o], a);
    u[o] = a > 0 ? a : 0;
  }
  __syncthreads();
  float a = B2[t];
  for (int k = 0; k < 512; k++) a = fmaf(u[k], W2[k * 256 + t], a);
  vn_out[g * 256 + t] = a > 0 ? a : 0;
}

__global__ void k_bnfin(const float* __restrict__ Ssum, const float* __restrict__ Ssq,
                        const float* __restrict__ g, const float* __restrict__ b,
                        float* __restrict__ scale, float* __restrict__ shift,
                        int NC, float invN) {
  int c = blockIdx.x * 256 + threadIdx.x;
  if (c >= NC) return;
  float mu = Ssum[c] * invN;
  float var = Ssq[c] * invN - mu * mu;
  float rs = rsqrtf(var + 1e-5f);
  float s = rs * g[c];
  scale[c] = s;
  shift[c] = b[c] - mu * s;
}

// out = t2*sc[c]+sh[c] (final BN, JK='last', no relu)
__global__ void k_final(const float* __restrict__ T2, const float* __restrict__ sc,
                        const float* __restrict__ sh, float* __restrict__ out) {
  int i = blockIdx.x * 256 + threadIdx.x; // 2097152 float4s
  int c4 = (i & 63) * 4;
  float4 v = *(const float4*)&T2[(size_t)i * 4];
  float4 s4 = *(const float4*)&sc[c4];
  float4 h4 = *(const float4*)&sh[c4];
  v.x = fmaf(v.x, s4.x, h4.x); v.y = fmaf(v.y, s4.y, h4.y);
  v.z = fmaf(v.z, s4.z, h4.z); v.w = fmaf(v.w, s4.w, h4.w);
  *(float4*)&out[(size_t)i * 4] = v;
}

extern "C" void kernel_launch(void* const* d_in, const int* in_sizes, int n_in,
                              void* d_out, int out_size, void* d_ws, size_t ws_size,
                              hipStream_t stream) {
  (void)in_sizes; (void)n_in; (void)out_size; (void)ws_size;
  const int*   atom_idx = (const int*)d_in[0];
  const int*   lei      = (const int*)d_in[1];
  const int*   eattr    = (const int*)d_in[2];
  const float* atom_emb = (const float*)d_in[4];
  const float* bemb_h   = (const float*)d_in[5];
  const float* elw      = (const float*)d_in[6];
  const float* elb      = (const float*)d_in[7];
  const float* bemb_l   = (const float*)d_in[8];
  const float* geps     = (const float*)d_in[9];
  const float* mw1      = (const float*)d_in[10];
  const float* mb1      = (const float*)d_in[11];
  const float* mbng     = (const float*)d_in[12];
  const float* mbnb     = (const float*)d_in[13];
  const float* mw2      = (const float*)d_in[14];
  const float* mb2      = (const float*)d_in[15];
  const float* obng     = (const float*)d_in[16];
  const float* obnb     = (const float*)d_in[17];
  const float* vne      = (const float*)d_in[18];
  const float* vw1      = (const float*)d_in[19];
  const float* vb1      = (const float*)d_in[20];
  const float* vw2      = (const float*)d_in[21];
  const float* vb2      = (const float*)d_in[22];
  float* out = (float*)d_out;

  // ws layout (33.55MB units): A_, X0T, X1T, YT, Z_, tail (~7MB)
  // aliases: T2=A_; H0=X0T; T1h=X1T, T1l=YT (bf16 pairs); Zh/Zl=Z_; PACKED=Z_.
  float* W   = (float*)d_ws;
  float* A_  = W;
  float* X0T = W + (size_t)FBUF;
  float* X1T = W + (size_t)2 * FBUF;
  float* YT  = W + (size_t)3 * FBUF;
  float* Z_  = W + (size_t)4 * FBUF;
  float* SM  = W + (size_t)5 * FBUF;
  float* EWT = SM;                   // 16
  float* S1S = SM + 256;             // 512
  float* S1Q = SM + 768;             // 512
  float* S2S = SM + 1280;            // 256
  float* S2Q = SM + 1536;            // 256  (S1S..S2Q contiguous 1536)
  float* SC2 = SM + 1792;            // 256
  float* SH2 = SM + 2048;            // 256
  float* VNA = SM + 2304;            // 32768
  float* VNB = SM + 35072;           // 32768
  int* ROWPTR = (int*)(SM + 67840);  // 32772
  int* POS    = ROWPTR + 32772;      // 32768
  int* COUNTS = POS + 32768;         // 32768
  int* CSR    = COUNTS + 32768;      // 262144
  unsigned short* W1hT = (unsigned short*)(SM + 428544);  // 5*512*256
  unsigned short* W1lT = (unsigned short*)(SM + 756224);
  unsigned short* W2hT = (unsigned short*)(SM + 1083904); // 5*256*512
  unsigned short* W2lT = (unsigned short*)(SM + 1411584);
  float* T2 = A_;
  float* H0 = X0T;
  unsigned short* T1h = (unsigned short*)X1T;
  unsigned short* T1l = (unsigned short*)YT;
  unsigned short* Zh  = (unsigned short*)Z_;
  unsigned short* Zl  = Zh + (size_t)NNODE * 256;
  int* PACKED = (int*)Z_;

  // ---- stage 1: dense learned-adjacency propagation (transposed space) ----
  k_zero<<<8192, 256, 0, stream>>>((uint4*)A_, 2097152);
  k_zero<<<8192, 256, 0, stream>>>((uint4*)PACKED, 2097152);
  k_zero<<<32, 256, 0, stream>>>((uint4*)COUNTS, 8192);
  k_ewtbl<<<1, 1024, 0, stream>>>(bemb_h, elw, elb, EWT);
  k_pack_adj<<<NEDGE / 256, 256, 0, stream>>>(lei, eattr, PACKED);
  k_unpack_adj<<<32768, 256, 0, stream>>>(PACKED, EWT, A_);
  k_addeye<<<NNODE / 256, 256, 0, stream>>>(A_);
  k_degnorm<<<B_G, 256, 0, stream>>>(A_);
  // weight transpose+split (once)
  k_wtsplit<<<dim3(8, 4, 5), 256, 0, stream>>>(mw1, W1hT, W1lT, 256, 512, 131072, 131072);
  k_wtsplit<<<dim3(4, 8, 5), 256, 0, stream>>>(mw2, W2hT, W2lT, 512, 256, 131072, 131072);
  k_feaT<<<32768, 256, 0, stream>>>(atom_idx, atom_emb, X0T, YT);
  // order=3: Xt_next = Xt @ A^T (== (A@X)^T), Yt accumulates
  k_mgemm<<<dim3(2, 2, B_G), 256, 0, stream>>>(X0T, A_, X1T, YT, 256, 256, 65536, 65536, 65536);
  k_mgemm<<<dim3(2, 2, B_G), 256, 0, stream>>>(X1T, A_, X0T, YT, 256, 256, 65536, 65536, 65536);
  k_mgemm<<<dim3(2, 2, B_G), 256, 0, stream>>>(X0T, A_, X1T, YT, 256, 256, 65536, 65536, 65536);
  // H0[n][e] = 0.25 * YT[e][n]
  k_transp<<<dim3(4, 4, B_G), 256, 0, stream>>>(YT, H0, 256, 256, 65536, 65536, 0.25f);

  // ---- CSR (once; edges invariant across layers) ----
  k_count<<<NEDGE / 256, 256, 0, stream>>>(lei, COUNTS);
  k_scan<<<B_G, 256, 0, stream>>>(COUNTS, ROWPTR, POS);
  k_fill<<<NEDGE / 256, 256, 0, stream>>>(lei, eattr, POS, CSR);

  // ---- GIN + virtual-node stack ----
  const float* vn_cur = vne; int vns = 0;   // layer0 vn = vn_emb broadcast
  float* vn_next = VNA;
  for (int l = 0; l < NL; l++) {
    const float* hsrc = (l == 0) ? H0 : T2;
    const float* hsc  = (l == 0) ? nullptr : SC2;
    const float* hsh  = (l == 0) ? nullptr : SH2;
    k_agg<<<NNODE / 4, 256, 0, stream>>>(hsrc, hsc, hsh, vn_cur, vns,
        bemb_l + (size_t)l * 16 * EMB, ROWPTR, CSR, geps, l, Zh, Zl);
    if (l < NL - 1)
      k_vn<<<B_G, 256, 0, stream>>>(hsrc, hsc, hsh, vn_cur, vns,
          vw1 + (size_t)l * EMB * 512, vb1 + (size_t)l * 512,
          vw2 + (size_t)l * 512 * EMB, vb2 + (size_t)l * EMB, vn_next);
    k_zero<<<2, 256, 0, stream>>>((uint4*)S1S, 384); // S1S,S1Q,S2S,S2Q
    k_bgemm<<<dim3(4, 256), 256, 0, stream>>>(Zh, Zl,
        W1hT + (size_t)l * 131072, W1lT + (size_t)l * 131072,
        mb1 + (size_t)l * 512, nullptr, T1h, T1l, S1S, S1Q, 256, 512);
    k_bnsplit<<<16384, 256, 0, stream>>>(T1h, T1l, S1S, S1Q,
        mbng + (size_t)l * 512, mbnb + (size_t)l * 512);
    k_bgemm<<<dim3(2, 256), 256, 0, stream>>>(T1h, T1l,
        W2hT + (size_t)l * 131072, W2lT + (size_t)l * 131072,
        mb2 + (size_t)l * 256, T2, nullptr, nullptr, S2S, S2Q, 512, 256);
    k_bnfin<<<1, 256, 0, stream>>>(S2S, S2Q, obng + (size_t)l * EMB,
        obnb + (size_t)l * EMB, SC2, SH2, 256, 1.0f / NNODE);
    if (l < NL - 1) {
      vn_cur = vn_next; vns = EMB;
      vn_next = (vn_next == VNA) ? VNB : VNA;
    }
  }
  k_final<<<8192, 256, 0, stream>>>(T2, SC2, SH2, out);
}